// Round 11
// baseline (173.328 us; speedup 1.0000x reference)
//
#include <hip/hip_runtime.h>
#include <hip/hip_fp16.h>

#define E_EDGES 640000
#define NN 20000
#define NC 16
#define PBIN 64   // fixed bin capacity per node (Poisson(32) tail ~1e-7)

#define Y00F 0.28209479177387814f
#define Y1CF 0.4886025119029199f
#define RS3  0.5773502691896258f
#define RS2  0.7071067811865476f

typedef float nf4 __attribute__((ext_vector_type(4)));
typedef unsigned int nu2 __attribute__((ext_vector_type(2)));

__device__ __forceinline__ unsigned pack2h(float a, float b) {
    unsigned short ua = __half_as_ushort(__float2half(a));
    unsigned short ub = __half_as_ushort(__float2half(b));
    return (unsigned)ua | ((unsigned)ub << 16);
}
__device__ __forceinline__ float lo_h(unsigned u) {
    return __half2float(__ushort_as_half((unsigned short)(u & 0xffffu)));
}
__device__ __forceinline__ float hi_h(unsigned u) {
    return __half2float(__ushort_as_half((unsigned short)(u >> 16)));
}

// rec = {pack2h(Y1C*ey, Y1C*ez), pack2h(Y1C*ex, t), A, sender}
// rbf_b = A * t^b * K_b  (K_b folded into gather coeffs)
// node cache: nodes_h[s*16+c] = {h(n0),h(n1a) | h(n1b),h(n1c)}  (8 B)

__global__ void init1_kernel(const float* __restrict__ coords,
                             const float* __restrict__ nodes0,
                             const float* __restrict__ nodes1,
                             float* __restrict__ out,
                             int* __restrict__ cnt,
                             int* __restrict__ ovf_count,
                             nu2* __restrict__ nodes_h) {
    int i = blockIdx.x * blockDim.x + threadIdx.x;
    if (i < 3 * NN) out[i] = coords[i];
    if (i < NN) cnt[i] = 0;
    if (i == 0) *ovf_count = 0;
    if (i < NN * NC) {
        float n0 = nodes0[i];
        const float* n1p = nodes1 + i * 3;
        nu2 v;
        v.x = pack2h(n0, n1p[0]);
        v.y = pack2h(n1p[1], n1p[2]);
        nodes_h[i] = v;
    }
}

__global__ void bin_kernel(const float* __restrict__ edges,
                           const int* __restrict__ senders,
                           const int* __restrict__ receivers,
                           int* __restrict__ cnt,
                           nf4* __restrict__ bins,
                           int* __restrict__ ovf_count,
                           int* __restrict__ ovf_list) {
    int e = blockIdx.x * blockDim.x + threadIdx.x;
    if (e >= E_EDGES) return;
    float ex = edges[3 * e + 0];
    float ey = edges[3 * e + 1];
    float ez = edges[3 * e + 2];
    int s  = senders[e];
    int rc = receivers[e];
    int pos = atomicAdd(&cnt[rc], 1);
    if (pos < PBIN) {
        float r2 = ex * ex + ey * ey + ez * ez;
        float r  = sqrtf(r2);
        float A  = __expf(-0.7f * r2);
        float t  = __expf(1.225f * r);
        nf4 rec;
        rec.x = __uint_as_float(pack2h(Y1CF * ey, Y1CF * ez));
        rec.y = __uint_as_float(pack2h(Y1CF * ex, t));
        rec.z = A;
        rec.w = __int_as_float(s);
        bins[(size_t)rc * PBIN + pos] = rec;
    } else {
        int k = atomicAdd(ovf_count, 1);
        if (k < 4096) ovf_list[k] = e;
    }
}

// gather: FOUR waves per node (16 j-slots), one block per node.
// Per lane: ~one iteration of 2 independent record chains.
__global__ __launch_bounds__(256) void gather1_kernel(
    const nf4*    __restrict__ bins,
    const int*    __restrict__ cnt,
    const nu2*    __restrict__ nodes_h,
    const float*  __restrict__ c00, const float* __restrict__ c01,
    const float*  __restrict__ c10, const float* __restrict__ c11,
    const float*  __restrict__ w000, const float* __restrict__ w011,
    const float*  __restrict__ w101, const float* __restrict__ w110,
    const float*  __restrict__ w111,
    float* __restrict__ out0, float* __restrict__ out1)
{
    int node = blockIdx.x;
    int t    = threadIdx.x;
    int c    = t & 15;
    int j    = t >> 4;         // 0..15 record slots
    int w    = t >> 6;         // wave index 0..3

    const float KB[5] = {1.0f, 0.58512723f, 0.11721218f, 0.00803909f, 1.8876652e-4f};
    float k00[5], k01[5], k10[5], k11[5];
#pragma unroll
    for (int b = 0; b < 5; b++) {
        k00[b] = c00[c * 5 + b] * KB[b];
        k01[b] = c01[c * 5 + b] * KB[b];
        k10[b] = c10[c * 5 + b] * KB[b];
        k11[b] = c11[c * 5 + b] * KB[b];
    }

    int n = cnt[node];
    n = (n < PBIN) ? n : PBIN;
    const nf4* base = bins + (size_t)node * PBIN;

    float a000 = 0.f, a110 = 0.f;
    float a011x = 0.f, a011y = 0.f, a011z = 0.f;
    float a101x = 0.f, a101y = 0.f, a101z = 0.f;
    float a111x = 0.f, a111y = 0.f, a111z = 0.f;

#define HORNER(k, t) fmaf((t), fmaf((t), fmaf((t), fmaf((t), k[4], k[3]), k[2]), k[1]), k[0])
#define COMPUTE(rec, nh)                                                   \
    {                                                                      \
        unsigned u0 = __float_as_uint(rec.x);                              \
        unsigned u1 = __float_as_uint(rec.y);                              \
        float py = lo_h(u0), pz = hi_h(u0);                                \
        float px = lo_h(u1), tf = hi_h(u1);                                \
        float Af = rec.z;                                                  \
        float rad00 = Af * HORNER(k00, tf);                                \
        float rad01 = Af * HORNER(k01, tf);                                \
        float rad10 = Af * HORNER(k10, tf);                                \
        float rad11 = Af * HORNER(k11, tf);                                \
        float n0  = lo_h(nh.x), n1a = hi_h(nh.x);                          \
        float n1b = lo_h(nh.y), n1c = hi_h(nh.y);                          \
        a000 = fmaf(n0, rad00, a000);                                      \
        a110 = fmaf(rad11, n1a * py + n1b * pz + n1c * px, a110);          \
        float kA = n0 * rad01;                                             \
        a011x = fmaf(kA, py, a011x);                                       \
        a011y = fmaf(kA, pz, a011y);                                       \
        a011z = fmaf(kA, px, a011z);                                       \
        a101x = fmaf(rad10, n1a, a101x);                                   \
        a101y = fmaf(rad10, n1b, a101y);                                   \
        a101z = fmaf(rad10, n1c, a101z);                                   \
        a111x = fmaf(rad11, n1b * px - n1c * pz, a111x);                   \
        a111y = fmaf(rad11, n1c * py - n1a * px, a111y);                   \
        a111z = fmaf(rad11, n1a * pz - n1b * py, a111z);                   \
    }

    int i = j;
    // main: 2 independent record chains, hand-interleaved
    for (; i + 16 < n; i += 32) {
        nf4 r0 = __builtin_nontemporal_load(&base[i]);
        nf4 r1 = __builtin_nontemporal_load(&base[i + 16]);
        int s0 = __float_as_int(r0.w);
        int s1 = __float_as_int(r1.w);
        nu2 nh0 = nodes_h[s0 * NC + c];
        nu2 nh1 = nodes_h[s1 * NC + c];
        COMPUTE(r0, nh0);
        COMPUTE(r1, nh1);
    }
    if (i < n) {
        nf4 r0 = __builtin_nontemporal_load(&base[i]);
        int s0 = __float_as_int(r0.w);
        nu2 nh0 = nodes_h[s0 * NC + c];
        COMPUTE(r0, nh0);
    }
#undef COMPUTE
#undef HORNER

    // intra-wave reduce over lane bits 4,5 (j within wave)
#define RED(v) v += __shfl_xor(v, 16, 64); v += __shfl_xor(v, 32, 64)
    RED(a000); RED(a110);
    RED(a011x); RED(a011y); RED(a011z);
    RED(a101x); RED(a101y); RED(a101z);
    RED(a111x); RED(a111y); RED(a111z);
#undef RED

    // cross-wave reduce: waves 1..3 write partials, wave 0 sums + stores
    __shared__ float red[3][16][11];
    if (w > 0 && (t & 63) < 16) {
        float* p = red[w - 1][c];
        p[0] = a000;  p[1] = a110;
        p[2] = a011x; p[3] = a011y; p[4]  = a011z;
        p[5] = a101x; p[6] = a101y; p[7]  = a101z;
        p[8] = a111x; p[9] = a111y; p[10] = a111z;
    }
    __syncthreads();
    if (w == 0 && t < 16) {
#pragma unroll
        for (int q = 0; q < 3; q++) {
            const float* p = red[q][c];
            a000  += p[0];  a110  += p[1];
            a011x += p[2];  a011y += p[3];  a011z += p[4];
            a101x += p[5];  a101y += p[6];  a101z += p[7];
            a111x += p[8];  a111y += p[9];  a111z += p[10];
        }
        float s000 = w000[c] * Y00F;
        float s110 = w110[c] * RS3;     // Y1C pre-folded into record
        float s011 = w011[c];
        float s101 = w101[c] * Y00F;
        float s111 = w111[c] * RS2;

        out0[node * 32 + c]      = s000 * a000;
        out0[node * 32 + 16 + c] = s110 * a110;

        float* o1 = out1 + node * 144;
        o1[3 * c + 0] = s011 * a011x;
        o1[3 * c + 1] = s011 * a011y;
        o1[3 * c + 2] = s011 * a011z;
        o1[3 * (16 + c) + 0] = s101 * a101x;
        o1[3 * (16 + c) + 1] = s101 * a101y;
        o1[3 * (16 + c) + 2] = s101 * a101z;
        o1[3 * (32 + c) + 0] = s111 * a111x;
        o1[3 * (32 + c) + 1] = s111 * a111y;
        o1[3 * (32 + c) + 2] = s111 * a111z;
    }
}

// cleanup: overflow edges (expected 0) — exact atomic path, after gather
__global__ void cleanup_kernel(
    const int* __restrict__ ovf_count, const int* __restrict__ ovf_list,
    const float* __restrict__ edges, const int* __restrict__ senders,
    const int* __restrict__ receivers,
    const float* __restrict__ nodes0, const float* __restrict__ nodes1,
    const float* __restrict__ c00, const float* __restrict__ c01,
    const float* __restrict__ c10, const float* __restrict__ c11,
    const float* __restrict__ w000, const float* __restrict__ w011,
    const float* __restrict__ w101, const float* __restrict__ w110,
    const float* __restrict__ w111,
    float* __restrict__ out0, float* __restrict__ out1)
{
    int nov = *ovf_count;
    if (nov > 4096) nov = 4096;
    for (int k = threadIdx.x; k < nov; k += blockDim.x) {
        int e = ovf_list[k];
        float ex = edges[3 * e + 0], ey = edges[3 * e + 1], ez = edges[3 * e + 2];
        float r = sqrtf(ex * ex + ey * ey + ez * ez);
        float rbf[5];
#pragma unroll
        for (int b = 0; b < 5; b++) {
            float d = r - 0.875f * (float)b;
            rbf[b] = __expf(-0.7f * d * d);
        }
        int s = senders[e], rc = receivers[e];
        const float* n0p = nodes0 + s * NC;
        const float* n1p = nodes1 + s * NC * 3;
        float* o0 = out0 + rc * 32;
        float* o1 = out1 + rc * 144;
        float pey = Y1CF * ey, pez = Y1CF * ez, pex = Y1CF * ex;
        for (int c = 0; c < NC; c++) {
            float rad00 = 0.f, rad01 = 0.f, rad10 = 0.f, rad11 = 0.f;
#pragma unroll
            for (int b = 0; b < 5; b++) {
                rad00 = fmaf(rbf[b], c00[c * 5 + b], rad00);
                rad01 = fmaf(rbf[b], c01[c * 5 + b], rad01);
                rad10 = fmaf(rbf[b], c10[c * 5 + b], rad10);
                rad11 = fmaf(rbf[b], c11[c * 5 + b], rad11);
            }
            float n0 = n0p[c];
            float n1a = n1p[3 * c + 0], n1b = n1p[3 * c + 1], n1c = n1p[3 * c + 2];
            float f11a = rad11 * pey, f11b = rad11 * pez, f11c = rad11 * pex;
            atomicAdd(&o0[c], w000[c] * n0 * rad00 * Y00F);
            atomicAdd(&o0[16 + c], w110[c] * RS3 * (n1a * f11a + n1b * f11b + n1c * f11c));
            float kA = w011[c] * n0 * rad01;
            atomicAdd(&o1[3 * c + 0], kA * pey);
            atomicAdd(&o1[3 * c + 1], kA * pez);
            atomicAdd(&o1[3 * c + 2], kA * pex);
            float kB = w101[c] * rad10 * Y00F;
            atomicAdd(&o1[3 * (16 + c) + 0], kB * n1a);
            atomicAdd(&o1[3 * (16 + c) + 1], kB * n1b);
            atomicAdd(&o1[3 * (16 + c) + 2], kB * n1c);
            float kC = w111[c] * RS2;
            atomicAdd(&o1[3 * (32 + c) + 0], kC * (n1b * f11c - n1c * f11b));
            atomicAdd(&o1[3 * (32 + c) + 1], kC * (n1c * f11a - n1a * f11c));
            atomicAdd(&o1[3 * (32 + c) + 2], kC * (n1a * f11b - n1b * f11a));
        }
    }
}

// ======================= fallback: pure atomic ============================
__global__ void init_out_fb(const float* __restrict__ coords,
                            float* __restrict__ out, int out_size) {
    int i = blockIdx.x * blockDim.x + threadIdx.x;
    if (i < 3 * NN) out[i] = coords[i];
    else if (i < out_size) out[i] = 0.0f;
}

__global__ __launch_bounds__(256) void tp_edges_fb(
    const float* __restrict__ edges, const int* __restrict__ senders,
    const int* __restrict__ receivers, const float* __restrict__ nodes0,
    const float* __restrict__ nodes1,
    const float* __restrict__ c00, const float* __restrict__ c01,
    const float* __restrict__ c10, const float* __restrict__ c11,
    const float* __restrict__ w000, const float* __restrict__ w011,
    const float* __restrict__ w101, const float* __restrict__ w110,
    const float* __restrict__ w111,
    float* __restrict__ out0, float* __restrict__ out1) {
    int e = blockIdx.x * blockDim.x + threadIdx.x;
    if (e >= E_EDGES) return;
    float ex = edges[3 * e + 0], ey = edges[3 * e + 1], ez = edges[3 * e + 2];
    float r = sqrtf(ex * ex + ey * ey + ez * ez);
    float rbf[5];
#pragma unroll
    for (int b = 0; b < 5; b++) {
        float d = r - 0.875f * (float)b;
        rbf[b] = __expf(-0.7f * d * d);
    }
    int s = senders[e], rc = receivers[e];
    const float* n0p = nodes0 + s * NC;
    const float* n1p = nodes1 + s * NC * 3;
    float* o0 = out0 + rc * 32;
    float* o1 = out1 + rc * 144;
    float pey = Y1CF * ey, pez = Y1CF * ez, pex = Y1CF * ex;
    for (int c = 0; c < NC; c++) {
        float rad00 = 0.f, rad01 = 0.f, rad10 = 0.f, rad11 = 0.f;
#pragma unroll
        for (int b = 0; b < 5; b++) {
            rad00 = fmaf(rbf[b], c00[c * 5 + b], rad00);
            rad01 = fmaf(rbf[b], c01[c * 5 + b], rad01);
            rad10 = fmaf(rbf[b], c10[c * 5 + b], rad10);
            rad11 = fmaf(rbf[b], c11[c * 5 + b], rad11);
        }
        float n0 = n0p[c];
        float n1a = n1p[3 * c + 0], n1b = n1p[3 * c + 1], n1c = n1p[3 * c + 2];
        float f11a = rad11 * pey, f11b = rad11 * pez, f11c = rad11 * pex;
        atomicAdd(&o0[c], w000[c] * n0 * rad00 * Y00F);
        atomicAdd(&o0[16 + c], w110[c] * RS3 * (n1a * f11a + n1b * f11b + n1c * f11c));
        float kA = w011[c] * n0 * rad01;
        atomicAdd(&o1[3 * c + 0], kA * pey);
        atomicAdd(&o1[3 * c + 1], kA * pez);
        atomicAdd(&o1[3 * c + 2], kA * pex);
        float kB = w101[c] * rad10 * Y00F;
        atomicAdd(&o1[3 * (16 + c) + 0], kB * n1a);
        atomicAdd(&o1[3 * (16 + c) + 1], kB * n1b);
        atomicAdd(&o1[3 * (16 + c) + 2], kB * n1c);
        float kC = w111[c] * RS2;
        atomicAdd(&o1[3 * (32 + c) + 0], kC * (n1b * f11c - n1c * f11b));
        atomicAdd(&o1[3 * (32 + c) + 1], kC * (n1c * f11a - n1a * f11c));
        atomicAdd(&o1[3 * (32 + c) + 2], kC * (n1a * f11b - n1b * f11a));
    }
}

extern "C" void kernel_launch(void* const* d_in, const int* in_sizes, int n_in,
                              void* d_out, int out_size, void* d_ws, size_t ws_size,
                              hipStream_t stream) {
    const float* coords    = (const float*)d_in[0];
    const float* nodes0    = (const float*)d_in[1];
    const float* nodes1    = (const float*)d_in[2];
    const float* edges     = (const float*)d_in[3];
    const int*   senders   = (const int*)  d_in[4];
    const int*   receivers = (const int*)  d_in[5];
    const float* c00       = (const float*)d_in[6];
    const float* c01       = (const float*)d_in[7];
    const float* c10       = (const float*)d_in[8];
    const float* c11       = (const float*)d_in[9];
    const float* w000      = (const float*)d_in[10];
    const float* w011      = (const float*)d_in[11];
    const float* w101      = (const float*)d_in[12];
    const float* w110      = (const float*)d_in[13];
    const float* w111      = (const float*)d_in[14];

    float* out  = (float*)d_out;
    float* out0 = out + 3 * NN;
    float* out1 = out + 3 * NN + NN * 2 * NC;

    size_t bins_bytes  = (size_t)NN * PBIN * 16;
    size_t nodes_bytes = (size_t)NN * NC * 8;
    size_t need1 = bins_bytes + nodes_bytes + (size_t)(NN + 1 + 4096) * 4;

    if (ws_size >= need1) {
        nf4* bins      = (nf4*)d_ws;
        nu2* nodes_h   = (nu2*)((char*)d_ws + bins_bytes);
        int* cnt       = (int*)((char*)d_ws + bins_bytes + nodes_bytes);  // NN
        int* ovf_count = cnt + NN;                                        // 1
        int* ovf_list  = ovf_count + 1;                                   // 4096

        init1_kernel<<<(NN * NC + 255) / 256, 256, 0, stream>>>(
            coords, nodes0, nodes1, out, cnt, ovf_count, nodes_h);
        bin_kernel<<<(E_EDGES + 255) / 256, 256, 0, stream>>>(
            edges, senders, receivers, cnt, bins, ovf_count, ovf_list);
        gather1_kernel<<<NN, 256, 0, stream>>>(
            bins, cnt, nodes_h,
            c00, c01, c10, c11, w000, w011, w101, w110, w111, out0, out1);
        cleanup_kernel<<<1, 256, 0, stream>>>(
            ovf_count, ovf_list, edges, senders, receivers, nodes0, nodes1,
            c00, c01, c10, c11, w000, w011, w101, w110, w111, out0, out1);
    } else {
        init_out_fb<<<(out_size + 255) / 256, 256, 0, stream>>>(coords, out, out_size);
        tp_edges_fb<<<(E_EDGES + 255) / 256, 256, 0, stream>>>(
            edges, senders, receivers, nodes0, nodes1,
            c00, c01, c10, c11, w000, w011, w101, w110, w111, out0, out1);
    }
}

// Round 12
// 165.822 us; speedup vs baseline: 1.0453x; 1.0453x over previous
//
#include <hip/hip_runtime.h>
#include <hip/hip_fp16.h>

#define E_EDGES 640000
#define NN 20000
#define NC 16
#define PBIN 64   // fixed bin capacity per node (Poisson(32) tail ~1e-7)

#define Y00F 0.28209479177387814f
#define Y1CF 0.4886025119029199f
#define RS3  0.5773502691896258f
#define RS2  0.7071067811865476f

typedef float nf4 __attribute__((ext_vector_type(4)));
typedef unsigned int nu2 __attribute__((ext_vector_type(2)));

__device__ __forceinline__ unsigned pack2h(float a, float b) {
    unsigned short ua = __half_as_ushort(__float2half(a));
    unsigned short ub = __half_as_ushort(__float2half(b));
    return (unsigned)ua | ((unsigned)ub << 16);
}
__device__ __forceinline__ float lo_h(unsigned u) {
    return __half2float(__ushort_as_half((unsigned short)(u & 0xffffu)));
}
__device__ __forceinline__ float hi_h(unsigned u) {
    return __half2float(__ushort_as_half((unsigned short)(u >> 16)));
}

// 8-byte record: {h(ey)|h(ez)<<16, h(ex)|sender<<16}  (sender < 65536)
// gather recomputes r2, A=exp(-0.7r2), t=exp(1.225r); rbf_b = A*t^b*K_b
// node cache: nodes_h[s*16+c] = {h(n0),h(n1a) | h(n1b),h(n1c)}  (8 B)

__global__ void init1_kernel(const float* __restrict__ coords,
                             const float* __restrict__ nodes0,
                             const float* __restrict__ nodes1,
                             float* __restrict__ out,
                             int* __restrict__ cnt,
                             int* __restrict__ ovf_count,
                             nu2* __restrict__ nodes_h) {
    int i = blockIdx.x * blockDim.x + threadIdx.x;
    if (i < 3 * NN) out[i] = coords[i];
    if (i < NN) cnt[i] = 0;
    if (i == 0) *ovf_count = 0;
    if (i < NN * NC) {
        float n0 = nodes0[i];
        const float* n1p = nodes1 + i * 3;
        nu2 v;
        v.x = pack2h(n0, n1p[0]);
        v.y = pack2h(n1p[1], n1p[2]);
        nodes_h[i] = v;
    }
}

__global__ void bin_kernel(const float* __restrict__ edges,
                           const int* __restrict__ senders,
                           const int* __restrict__ receivers,
                           int* __restrict__ cnt,
                           nu2* __restrict__ bins,
                           int* __restrict__ ovf_count,
                           int* __restrict__ ovf_list) {
    int e = blockIdx.x * blockDim.x + threadIdx.x;
    if (e >= E_EDGES) return;
    float ex = edges[3 * e + 0];
    float ey = edges[3 * e + 1];
    float ez = edges[3 * e + 2];
    int s  = senders[e];
    int rc = receivers[e];
    int pos = atomicAdd(&cnt[rc], 1);
    if (pos < PBIN) {
        nu2 rec;
        rec.x = pack2h(ey, ez);
        rec.y = (unsigned)__half_as_ushort(__float2half(ex)) | ((unsigned)s << 16);
        bins[(size_t)rc * PBIN + pos] = rec;
    } else {
        int k = atomicAdd(ovf_count, 1);
        if (k < 4096) ovf_list[k] = e;
    }
}

// gather: TWO waves per node (8 j-slots), 2 nodes per 256-thread block.
__global__ __launch_bounds__(256) void gather1_kernel(
    const nu2*    __restrict__ bins,
    const int*    __restrict__ cnt,
    const nu2*    __restrict__ nodes_h,
    const float*  __restrict__ c00, const float* __restrict__ c01,
    const float*  __restrict__ c10, const float* __restrict__ c11,
    const float*  __restrict__ w000, const float* __restrict__ w011,
    const float*  __restrict__ w101, const float* __restrict__ w110,
    const float*  __restrict__ w111,
    float* __restrict__ out0, float* __restrict__ out1)
{
    int t    = threadIdx.x;
    int slot = t >> 7;                         // 2 nodes per block
    int node = blockIdx.x * 2 + slot;          // NN even
    int tid  = t & 127;
    int c    = tid & 15;
    int j    = tid >> 4;                       // 0..7 record slots

    const float KB[5] = {1.0f, 0.58512723f, 0.11721218f, 0.00803909f, 1.8876652e-4f};
    float k00[5], k01[5], k10[5], k11[5];
#pragma unroll
    for (int b = 0; b < 5; b++) {
        k00[b] = c00[c * 5 + b] * KB[b];
        k01[b] = c01[c * 5 + b] * KB[b];
        k10[b] = c10[c * 5 + b] * KB[b];
        k11[b] = c11[c * 5 + b] * KB[b];
    }

    int n = cnt[node];
    n = (n < PBIN) ? n : PBIN;
    const nu2* base = bins + (size_t)node * PBIN;

    float a000 = 0.f, a110 = 0.f;
    float a011x = 0.f, a011y = 0.f, a011z = 0.f;
    float a101x = 0.f, a101y = 0.f, a101z = 0.f;
    float a111x = 0.f, a111y = 0.f, a111z = 0.f;

#define HORNER(k, t) fmaf((t), fmaf((t), fmaf((t), fmaf((t), k[4], k[3]), k[2]), k[1]), k[0])
#define COMPUTE(rec, nh)                                                   \
    {                                                                      \
        float py = lo_h(rec.x), pz = hi_h(rec.x);                          \
        float px = lo_h(rec.y);                                            \
        float r2 = fmaf(px, px, fmaf(py, py, pz * pz));                    \
        float r  = sqrtf(r2);                                              \
        float Af = __expf(-0.7f * r2);                                     \
        float tf = __expf(1.225f * r);                                     \
        float rad00 = Af * HORNER(k00, tf);                                \
        float rad01 = Af * HORNER(k01, tf);                                \
        float rad10 = Af * HORNER(k10, tf);                                \
        float rad11 = Af * HORNER(k11, tf);                                \
        float n0  = lo_h(nh.x), n1a = hi_h(nh.x);                          \
        float n1b = lo_h(nh.y), n1c = hi_h(nh.y);                          \
        a000 = fmaf(n0, rad00, a000);                                      \
        a110 = fmaf(rad11, n1a * py + n1b * pz + n1c * px, a110);          \
        float kA = n0 * rad01;                                             \
        a011x = fmaf(kA, py, a011x);                                       \
        a011y = fmaf(kA, pz, a011y);                                       \
        a011z = fmaf(kA, px, a011z);                                       \
        a101x = fmaf(rad10, n1a, a101x);                                   \
        a101y = fmaf(rad10, n1b, a101y);                                   \
        a101z = fmaf(rad10, n1c, a101z);                                   \
        a111x = fmaf(rad11, n1b * px - n1c * pz, a111x);                   \
        a111y = fmaf(rad11, n1c * py - n1a * px, a111y);                   \
        a111z = fmaf(rad11, n1a * pz - n1b * py, a111z);                   \
    }

    int i = j;
    for (; i + 8 < n; i += 16) {
        nu2 r0 = __builtin_nontemporal_load(&base[i]);
        nu2 r1 = __builtin_nontemporal_load(&base[i + 8]);
        int s0 = r0.y >> 16;
        int s1 = r1.y >> 16;
        nu2 nh0 = nodes_h[s0 * NC + c];
        nu2 nh1 = nodes_h[s1 * NC + c];
        COMPUTE(r0, nh0);
        COMPUTE(r1, nh1);
    }
    if (i < n) {
        nu2 r0 = __builtin_nontemporal_load(&base[i]);
        int s0 = r0.y >> 16;
        nu2 nh0 = nodes_h[s0 * NC + c];
        COMPUTE(r0, nh0);
    }
#undef COMPUTE
#undef HORNER

    // intra-wave reduce over lane bits 4,5
#define RED(v) v += __shfl_xor(v, 16, 64); v += __shfl_xor(v, 32, 64)
    RED(a000); RED(a110);
    RED(a011x); RED(a011y); RED(a011z);
    RED(a101x); RED(a101y); RED(a101z);
    RED(a111x); RED(a111y); RED(a111z);
#undef RED

    // cross-wave reduce: first wave writes partials, second adds + stores
    __shared__ float red[2][16][11];
    int half = tid >> 6;
    if (half == 0 && (tid & 63) < 16) {
        float* p = red[slot][c];
        p[0] = a000;  p[1] = a110;
        p[2] = a011x; p[3] = a011y; p[4]  = a011z;
        p[5] = a101x; p[6] = a101y; p[7]  = a101z;
        p[8] = a111x; p[9] = a111y; p[10] = a111z;
    }
    __syncthreads();
    if (half == 1 && (tid & 63) < 16) {
        const float* p = red[slot][c];
        a000  += p[0];  a110  += p[1];
        a011x += p[2];  a011y += p[3];  a011z += p[4];
        a101x += p[5];  a101y += p[6];  a101z += p[7];
        a111x += p[8];  a111y += p[9];  a111z += p[10];

        // Y1C folded here (records hold raw e)
        float s000 = w000[c] * Y00F;
        float s110 = w110[c] * RS3 * Y1CF;
        float s011 = w011[c] * Y1CF;
        float s101 = w101[c] * Y00F;
        float s111 = w111[c] * RS2 * Y1CF;

        out0[node * 32 + c]      = s000 * a000;
        out0[node * 32 + 16 + c] = s110 * a110;

        float* o1 = out1 + node * 144;
        o1[3 * c + 0] = s011 * a011x;
        o1[3 * c + 1] = s011 * a011y;
        o1[3 * c + 2] = s011 * a011z;
        o1[3 * (16 + c) + 0] = s101 * a101x;
        o1[3 * (16 + c) + 1] = s101 * a101y;
        o1[3 * (16 + c) + 2] = s101 * a101z;
        o1[3 * (32 + c) + 0] = s111 * a111x;
        o1[3 * (32 + c) + 1] = s111 * a111y;
        o1[3 * (32 + c) + 2] = s111 * a111z;
    }
}

// cleanup: overflow edges (expected 0) — exact atomic path, after gather
__global__ void cleanup_kernel(
    const int* __restrict__ ovf_count, const int* __restrict__ ovf_list,
    const float* __restrict__ edges, const int* __restrict__ senders,
    const int* __restrict__ receivers,
    const float* __restrict__ nodes0, const float* __restrict__ nodes1,
    const float* __restrict__ c00, const float* __restrict__ c01,
    const float* __restrict__ c10, const float* __restrict__ c11,
    const float* __restrict__ w000, const float* __restrict__ w011,
    const float* __restrict__ w101, const float* __restrict__ w110,
    const float* __restrict__ w111,
    float* __restrict__ out0, float* __restrict__ out1)
{
    int nov = *ovf_count;
    if (nov > 4096) nov = 4096;
    for (int k = threadIdx.x; k < nov; k += blockDim.x) {
        int e = ovf_list[k];
        float ex = edges[3 * e + 0], ey = edges[3 * e + 1], ez = edges[3 * e + 2];
        float r = sqrtf(ex * ex + ey * ey + ez * ez);
        float rbf[5];
#pragma unroll
        for (int b = 0; b < 5; b++) {
            float d = r - 0.875f * (float)b;
            rbf[b] = __expf(-0.7f * d * d);
        }
        int s = senders[e], rc = receivers[e];
        const float* n0p = nodes0 + s * NC;
        const float* n1p = nodes1 + s * NC * 3;
        float* o0 = out0 + rc * 32;
        float* o1 = out1 + rc * 144;
        float pey = Y1CF * ey, pez = Y1CF * ez, pex = Y1CF * ex;
        for (int c = 0; c < NC; c++) {
            float rad00 = 0.f, rad01 = 0.f, rad10 = 0.f, rad11 = 0.f;
#pragma unroll
            for (int b = 0; b < 5; b++) {
                rad00 = fmaf(rbf[b], c00[c * 5 + b], rad00);
                rad01 = fmaf(rbf[b], c01[c * 5 + b], rad01);
                rad10 = fmaf(rbf[b], c10[c * 5 + b], rad10);
                rad11 = fmaf(rbf[b], c11[c * 5 + b], rad11);
            }
            float n0 = n0p[c];
            float n1a = n1p[3 * c + 0], n1b = n1p[3 * c + 1], n1c = n1p[3 * c + 2];
            float f11a = rad11 * pey, f11b = rad11 * pez, f11c = rad11 * pex;
            atomicAdd(&o0[c], w000[c] * n0 * rad00 * Y00F);
            atomicAdd(&o0[16 + c], w110[c] * RS3 * (n1a * f11a + n1b * f11b + n1c * f11c));
            float kA = w011[c] * n0 * rad01;
            atomicAdd(&o1[3 * c + 0], kA * pey);
            atomicAdd(&o1[3 * c + 1], kA * pez);
            atomicAdd(&o1[3 * c + 2], kA * pex);
            float kB = w101[c] * rad10 * Y00F;
            atomicAdd(&o1[3 * (16 + c) + 0], kB * n1a);
            atomicAdd(&o1[3 * (16 + c) + 1], kB * n1b);
            atomicAdd(&o1[3 * (16 + c) + 2], kB * n1c);
            float kC = w111[c] * RS2;
            atomicAdd(&o1[3 * (32 + c) + 0], kC * (n1b * f11c - n1c * f11b));
            atomicAdd(&o1[3 * (32 + c) + 1], kC * (n1c * f11a - n1a * f11c));
            atomicAdd(&o1[3 * (32 + c) + 2], kC * (n1a * f11b - n1b * f11a));
        }
    }
}

// ======================= fallback: pure atomic ============================
__global__ void init_out_fb(const float* __restrict__ coords,
                            float* __restrict__ out, int out_size) {
    int i = blockIdx.x * blockDim.x + threadIdx.x;
    if (i < 3 * NN) out[i] = coords[i];
    else if (i < out_size) out[i] = 0.0f;
}

__global__ __launch_bounds__(256) void tp_edges_fb(
    const float* __restrict__ edges, const int* __restrict__ senders,
    const int* __restrict__ receivers, const float* __restrict__ nodes0,
    const float* __restrict__ nodes1,
    const float* __restrict__ c00, const float* __restrict__ c01,
    const float* __restrict__ c10, const float* __restrict__ c11,
    const float* __restrict__ w000, const float* __restrict__ w011,
    const float* __restrict__ w101, const float* __restrict__ w110,
    const float* __restrict__ w111,
    float* __restrict__ out0, float* __restrict__ out1) {
    int e = blockIdx.x * blockDim.x + threadIdx.x;
    if (e >= E_EDGES) return;
    float ex = edges[3 * e + 0], ey = edges[3 * e + 1], ez = edges[3 * e + 2];
    float r = sqrtf(ex * ex + ey * ey + ez * ez);
    float rbf[5];
#pragma unroll
    for (int b = 0; b < 5; b++) {
        float d = r - 0.875f * (float)b;
        rbf[b] = __expf(-0.7f * d * d);
    }
    int s = senders[e], rc = receivers[e];
    const float* n0p = nodes0 + s * NC;
    const float* n1p = nodes1 + s * NC * 3;
    float* o0 = out0 + rc * 32;
    float* o1 = out1 + rc * 144;
    float pey = Y1CF * ey, pez = Y1CF * ez, pex = Y1CF * ex;
    for (int c = 0; c < NC; c++) {
        float rad00 = 0.f, rad01 = 0.f, rad10 = 0.f, rad11 = 0.f;
#pragma unroll
        for (int b = 0; b < 5; b++) {
            rad00 = fmaf(rbf[b], c00[c * 5 + b], rad00);
            rad01 = fmaf(rbf[b], c01[c * 5 + b], rad01);
            rad10 = fmaf(rbf[b], c10[c * 5 + b], rad10);
            rad11 = fmaf(rbf[b], c11[c * 5 + b], rad11);
        }
        float n0 = n0p[c];
        float n1a = n1p[3 * c + 0], n1b = n1p[3 * c + 1], n1c = n1p[3 * c + 2];
        float f11a = rad11 * pey, f11b = rad11 * pez, f11c = rad11 * pex;
        atomicAdd(&o0[c], w000[c] * n0 * rad00 * Y00F);
        atomicAdd(&o0[16 + c], w110[c] * RS3 * (n1a * f11a + n1b * f11b + n1c * f11c));
        float kA = w011[c] * n0 * rad01;
        atomicAdd(&o1[3 * c + 0], kA * pey);
        atomicAdd(&o1[3 * c + 1], kA * pez);
        atomicAdd(&o1[3 * c + 2], kA * pex);
        float kB = w101[c] * rad10 * Y00F;
        atomicAdd(&o1[3 * (16 + c) + 0], kB * n1a);
        atomicAdd(&o1[3 * (16 + c) + 1], kB * n1b);
        atomicAdd(&o1[3 * (16 + c) + 2], kB * n1c);
        float kC = w111[c] * RS2;
        atomicAdd(&o1[3 * (32 + c) + 0], kC * (n1b * f11c - n1c * f11b));
        atomicAdd(&o1[3 * (32 + c) + 1], kC * (n1c * f11a - n1a * f11c));
        atomicAdd(&o1[3 * (32 + c) + 2], kC * (n1a * f11b - n1b * f11a));
    }
}

extern "C" void kernel_launch(void* const* d_in, const int* in_sizes, int n_in,
                              void* d_out, int out_size, void* d_ws, size_t ws_size,
                              hipStream_t stream) {
    const float* coords    = (const float*)d_in[0];
    const float* nodes0    = (const float*)d_in[1];
    const float* nodes1    = (const float*)d_in[2];
    const float* edges     = (const float*)d_in[3];
    const int*   senders   = (const int*)  d_in[4];
    const int*   receivers = (const int*)  d_in[5];
    const float* c00       = (const float*)d_in[6];
    const float* c01       = (const float*)d_in[7];
    const float* c10       = (const float*)d_in[8];
    const float* c11       = (const float*)d_in[9];
    const float* w000      = (const float*)d_in[10];
    const float* w011      = (const float*)d_in[11];
    const float* w101      = (const float*)d_in[12];
    const float* w110      = (const float*)d_in[13];
    const float* w111      = (const float*)d_in[14];

    float* out  = (float*)d_out;
    float* out0 = out + 3 * NN;
    float* out1 = out + 3 * NN + NN * 2 * NC;

    size_t bins_bytes  = (size_t)NN * PBIN * 8;
    size_t nodes_bytes = (size_t)NN * NC * 8;
    size_t need1 = bins_bytes + nodes_bytes + (size_t)(NN + 1 + 4096) * 4;

    if (ws_size >= need1) {
        nu2* bins      = (nu2*)d_ws;
        nu2* nodes_h   = (nu2*)((char*)d_ws + bins_bytes);
        int* cnt       = (int*)((char*)d_ws + bins_bytes + nodes_bytes);  // NN
        int* ovf_count = cnt + NN;                                        // 1
        int* ovf_list  = ovf_count + 1;                                   // 4096

        init1_kernel<<<(NN * NC + 255) / 256, 256, 0, stream>>>(
            coords, nodes0, nodes1, out, cnt, ovf_count, nodes_h);
        bin_kernel<<<(E_EDGES + 255) / 256, 256, 0, stream>>>(
            edges, senders, receivers, cnt, bins, ovf_count, ovf_list);
        gather1_kernel<<<NN / 2, 256, 0, stream>>>(
            bins, cnt, nodes_h,
            c00, c01, c10, c11, w000, w011, w101, w110, w111, out0, out1);
        cleanup_kernel<<<1, 256, 0, stream>>>(
            ovf_count, ovf_list, edges, senders, receivers, nodes0, nodes1,
            c00, c01, c10, c11, w000, w011, w101, w110, w111, out0, out1);
    } else {
        init_out_fb<<<(out_size + 255) / 256, 256, 0, stream>>>(coords, out, out_size);
        tp_edges_fb<<<(E_EDGES + 255) / 256, 256, 0, stream>>>(
            edges, senders, receivers, nodes0, nodes1,
            c00, c01, c10, c11, w000, w011, w101, w110, w111, out0, out1);
    }
}

// Round 13
// 164.973 us; speedup vs baseline: 1.0506x; 1.0051x over previous
//
#include <hip/hip_runtime.h>
#include <hip/hip_fp16.h>

#define E_EDGES 640000
#define NN 20000
#define NC 16
#define PBIN 64   // fixed bin capacity per node (Poisson(32) tail ~1e-7)

#define Y00F 0.28209479177387814f
#define Y1CF 0.4886025119029199f
#define RS3  0.5773502691896258f
#define RS2  0.7071067811865476f

typedef unsigned int nu2 __attribute__((ext_vector_type(2)));

__device__ __forceinline__ unsigned pack2h(float a, float b) {
    unsigned short ua = __half_as_ushort(__float2half(a));
    unsigned short ub = __half_as_ushort(__float2half(b));
    return (unsigned)ua | ((unsigned)ub << 16);
}
__device__ __forceinline__ float lo_h(unsigned u) {
    return __half2float(__ushort_as_half((unsigned short)(u & 0xffffu)));
}
__device__ __forceinline__ float hi_h(unsigned u) {
    return __half2float(__ushort_as_half((unsigned short)(u >> 16)));
}

// 8-byte record: {h(ey)|h(ez)<<16, h(ex)|sender<<16}  (sender < 65536)
// gather recomputes r2, A=exp(-0.7r2), t=exp(1.225r); rbf_b = A*t^b*K_b
// node cache: nodes_h[s*16+c] = {h(n0),h(n1a) | h(n1b),h(n1c)}  (8 B)

__global__ void init1_kernel(const float* __restrict__ coords,
                             const float* __restrict__ nodes0,
                             const float* __restrict__ nodes1,
                             float* __restrict__ out,
                             int* __restrict__ cnt,
                             int* __restrict__ ovf_count,
                             nu2* __restrict__ nodes_h) {
    int i = blockIdx.x * blockDim.x + threadIdx.x;
    if (i < 3 * NN) out[i] = coords[i];
    if (i < NN) cnt[i] = 0;
    if (i == 0) *ovf_count = 0;
    if (i < NN * NC) {
        float n0 = nodes0[i];
        const float* n1p = nodes1 + i * 3;
        nu2 v;
        v.x = pack2h(n0, n1p[0]);
        v.y = pack2h(n1p[1], n1p[2]);
        nodes_h[i] = v;
    }
}

__global__ void bin_kernel(const float* __restrict__ edges,
                           const int* __restrict__ senders,
                           const int* __restrict__ receivers,
                           int* __restrict__ cnt,
                           nu2* __restrict__ bins,
                           int* __restrict__ ovf_count,
                           int* __restrict__ ovf_list) {
    int e = blockIdx.x * blockDim.x + threadIdx.x;
    if (e >= E_EDGES) return;
    float ex = edges[3 * e + 0];
    float ey = edges[3 * e + 1];
    float ez = edges[3 * e + 2];
    int s  = senders[e];
    int rc = receivers[e];
    int pos = atomicAdd(&cnt[rc], 1);
    if (pos < PBIN) {
        nu2 rec;
        rec.x = pack2h(ey, ez);
        rec.y = (unsigned)__half_as_ushort(__float2half(ex)) | ((unsigned)s << 16);
        bins[(size_t)rc * PBIN + pos] = rec;
    } else {
        int k = atomicAdd(ovf_count, 1);
        if (k < 4096) ovf_list[k] = e;
    }
}

// gather: ONE wave per node, 4 nodes per 256-thread block.
// No LDS, no __syncthreads; shfl-only reduction.
__global__ __launch_bounds__(256) void gather1_kernel(
    const nu2*    __restrict__ bins,
    const int*    __restrict__ cnt,
    const nu2*    __restrict__ nodes_h,
    const float*  __restrict__ c00, const float* __restrict__ c01,
    const float*  __restrict__ c10, const float* __restrict__ c11,
    const float*  __restrict__ w000, const float* __restrict__ w011,
    const float*  __restrict__ w101, const float* __restrict__ w110,
    const float*  __restrict__ w111,
    float* __restrict__ out0, float* __restrict__ out1)
{
    int t    = threadIdx.x;
    int node = blockIdx.x * 4 + (t >> 6);      // NN multiple of 4
    int lane = t & 63;
    int c    = lane & 15;
    int j    = lane >> 4;                      // 0..3 record slots

    const float KB[5] = {1.0f, 0.58512723f, 0.11721218f, 0.00803909f, 1.8876652e-4f};
    float k00[5], k01[5], k10[5], k11[5];
#pragma unroll
    for (int b = 0; b < 5; b++) {
        k00[b] = c00[c * 5 + b] * KB[b];
        k01[b] = c01[c * 5 + b] * KB[b];
        k10[b] = c10[c * 5 + b] * KB[b];
        k11[b] = c11[c * 5 + b] * KB[b];
    }

    int n = cnt[node];
    n = (n < PBIN) ? n : PBIN;
    const nu2* base = bins + (size_t)node * PBIN;

    float a000 = 0.f, a110 = 0.f;
    float a011x = 0.f, a011y = 0.f, a011z = 0.f;
    float a101x = 0.f, a101y = 0.f, a101z = 0.f;
    float a111x = 0.f, a111y = 0.f, a111z = 0.f;

#define HORNER(k, t) fmaf((t), fmaf((t), fmaf((t), fmaf((t), k[4], k[3]), k[2]), k[1]), k[0])
#define COMPUTE(rec, nh)                                                   \
    {                                                                      \
        float py = lo_h(rec.x), pz = hi_h(rec.x);                          \
        float px = lo_h(rec.y);                                            \
        float r2 = fmaf(px, px, fmaf(py, py, pz * pz));                    \
        float r  = sqrtf(r2);                                              \
        float Af = __expf(-0.7f * r2);                                     \
        float tf = __expf(1.225f * r);                                     \
        float rad00 = Af * HORNER(k00, tf);                                \
        float rad01 = Af * HORNER(k01, tf);                                \
        float rad10 = Af * HORNER(k10, tf);                                \
        float rad11 = Af * HORNER(k11, tf);                                \
        float n0  = lo_h(nh.x), n1a = hi_h(nh.x);                          \
        float n1b = lo_h(nh.y), n1c = hi_h(nh.y);                          \
        a000 = fmaf(n0, rad00, a000);                                      \
        a110 = fmaf(rad11, n1a * py + n1b * pz + n1c * px, a110);          \
        float kA = n0 * rad01;                                             \
        a011x = fmaf(kA, py, a011x);                                       \
        a011y = fmaf(kA, pz, a011y);                                       \
        a011z = fmaf(kA, px, a011z);                                       \
        a101x = fmaf(rad10, n1a, a101x);                                   \
        a101y = fmaf(rad10, n1b, a101y);                                   \
        a101z = fmaf(rad10, n1c, a101z);                                   \
        a111x = fmaf(rad11, n1b * px - n1c * pz, a111x);                   \
        a111y = fmaf(rad11, n1c * py - n1a * px, a111y);                   \
        a111z = fmaf(rad11, n1a * pz - n1b * py, a111z);                   \
    }

    int i = j;
    for (; i + 4 < n; i += 8) {
        nu2 r0 = __builtin_nontemporal_load(&base[i]);
        nu2 r1 = __builtin_nontemporal_load(&base[i + 4]);
        int s0 = r0.y >> 16;
        int s1 = r1.y >> 16;
        nu2 nh0 = nodes_h[s0 * NC + c];
        nu2 nh1 = nodes_h[s1 * NC + c];
        COMPUTE(r0, nh0);
        COMPUTE(r1, nh1);
    }
    if (i < n) {
        nu2 r0 = __builtin_nontemporal_load(&base[i]);
        int s0 = r0.y >> 16;
        nu2 nh0 = nodes_h[s0 * NC + c];
        COMPUTE(r0, nh0);
    }
#undef COMPUTE
#undef HORNER

    // intra-wave reduce over j (lane bits 4,5)
#define RED(v) v += __shfl_xor(v, 16, 64); v += __shfl_xor(v, 32, 64)
    RED(a000); RED(a110);
    RED(a011x); RED(a011y); RED(a011z);
    RED(a101x); RED(a101y); RED(a101z);
    RED(a111x); RED(a111y); RED(a111z);
#undef RED

    if (j == 0) {
        // Y1C folded here (records hold raw e)
        float s000 = w000[c] * Y00F;
        float s110 = w110[c] * RS3 * Y1CF;
        float s011 = w011[c] * Y1CF;
        float s101 = w101[c] * Y00F;
        float s111 = w111[c] * RS2 * Y1CF;

        out0[node * 32 + c]      = s000 * a000;
        out0[node * 32 + 16 + c] = s110 * a110;

        float* o1 = out1 + node * 144;
        o1[3 * c + 0] = s011 * a011x;
        o1[3 * c + 1] = s011 * a011y;
        o1[3 * c + 2] = s011 * a011z;
        o1[3 * (16 + c) + 0] = s101 * a101x;
        o1[3 * (16 + c) + 1] = s101 * a101y;
        o1[3 * (16 + c) + 2] = s101 * a101z;
        o1[3 * (32 + c) + 0] = s111 * a111x;
        o1[3 * (32 + c) + 1] = s111 * a111y;
        o1[3 * (32 + c) + 2] = s111 * a111z;
    }
}

// cleanup: overflow edges (expected 0) — exact atomic path, after gather
__global__ void cleanup_kernel(
    const int* __restrict__ ovf_count, const int* __restrict__ ovf_list,
    const float* __restrict__ edges, const int* __restrict__ senders,
    const int* __restrict__ receivers,
    const float* __restrict__ nodes0, const float* __restrict__ nodes1,
    const float* __restrict__ c00, const float* __restrict__ c01,
    const float* __restrict__ c10, const float* __restrict__ c11,
    const float* __restrict__ w000, const float* __restrict__ w011,
    const float* __restrict__ w101, const float* __restrict__ w110,
    const float* __restrict__ w111,
    float* __restrict__ out0, float* __restrict__ out1)
{
    int nov = *ovf_count;
    if (nov > 4096) nov = 4096;
    for (int k = threadIdx.x; k < nov; k += blockDim.x) {
        int e = ovf_list[k];
        float ex = edges[3 * e + 0], ey = edges[3 * e + 1], ez = edges[3 * e + 2];
        float r = sqrtf(ex * ex + ey * ey + ez * ez);
        float rbf[5];
#pragma unroll
        for (int b = 0; b < 5; b++) {
            float d = r - 0.875f * (float)b;
            rbf[b] = __expf(-0.7f * d * d);
        }
        int s = senders[e], rc = receivers[e];
        const float* n0p = nodes0 + s * NC;
        const float* n1p = nodes1 + s * NC * 3;
        float* o0 = out0 + rc * 32;
        float* o1 = out1 + rc * 144;
        float pey = Y1CF * ey, pez = Y1CF * ez, pex = Y1CF * ex;
        for (int c = 0; c < NC; c++) {
            float rad00 = 0.f, rad01 = 0.f, rad10 = 0.f, rad11 = 0.f;
#pragma unroll
            for (int b = 0; b < 5; b++) {
                rad00 = fmaf(rbf[b], c00[c * 5 + b], rad00);
                rad01 = fmaf(rbf[b], c01[c * 5 + b], rad01);
                rad10 = fmaf(rbf[b], c10[c * 5 + b], rad10);
                rad11 = fmaf(rbf[b], c11[c * 5 + b], rad11);
            }
            float n0 = n0p[c];
            float n1a = n1p[3 * c + 0], n1b = n1p[3 * c + 1], n1c = n1p[3 * c + 2];
            float f11a = rad11 * pey, f11b = rad11 * pez, f11c = rad11 * pex;
            atomicAdd(&o0[c], w000[c] * n0 * rad00 * Y00F);
            atomicAdd(&o0[16 + c], w110[c] * RS3 * (n1a * f11a + n1b * f11b + n1c * f11c));
            float kA = w011[c] * n0 * rad01;
            atomicAdd(&o1[3 * c + 0], kA * pey);
            atomicAdd(&o1[3 * c + 1], kA * pez);
            atomicAdd(&o1[3 * c + 2], kA * pex);
            float kB = w101[c] * rad10 * Y00F;
            atomicAdd(&o1[3 * (16 + c) + 0], kB * n1a);
            atomicAdd(&o1[3 * (16 + c) + 1], kB * n1b);
            atomicAdd(&o1[3 * (16 + c) + 2], kB * n1c);
            float kC = w111[c] * RS2;
            atomicAdd(&o1[3 * (32 + c) + 0], kC * (n1b * f11c - n1c * f11b));
            atomicAdd(&o1[3 * (32 + c) + 1], kC * (n1c * f11a - n1a * f11c));
            atomicAdd(&o1[3 * (32 + c) + 2], kC * (n1a * f11b - n1b * f11a));
        }
    }
}

// ======================= fallback: pure atomic ============================
__global__ void init_out_fb(const float* __restrict__ coords,
                            float* __restrict__ out, int out_size) {
    int i = blockIdx.x * blockDim.x + threadIdx.x;
    if (i < 3 * NN) out[i] = coords[i];
    else if (i < out_size) out[i] = 0.0f;
}

__global__ __launch_bounds__(256) void tp_edges_fb(
    const float* __restrict__ edges, const int* __restrict__ senders,
    const int* __restrict__ receivers, const float* __restrict__ nodes0,
    const float* __restrict__ nodes1,
    const float* __restrict__ c00, const float* __restrict__ c01,
    const float* __restrict__ c10, const float* __restrict__ c11,
    const float* __restrict__ w000, const float* __restrict__ w011,
    const float* __restrict__ w101, const float* __restrict__ w110,
    const float* __restrict__ w111,
    float* __restrict__ out0, float* __restrict__ out1) {
    int e = blockIdx.x * blockDim.x + threadIdx.x;
    if (e >= E_EDGES) return;
    float ex = edges[3 * e + 0], ey = edges[3 * e + 1], ez = edges[3 * e + 2];
    float r = sqrtf(ex * ex + ey * ey + ez * ez);
    float rbf[5];
#pragma unroll
    for (int b = 0; b < 5; b++) {
        float d = r - 0.875f * (float)b;
        rbf[b] = __expf(-0.7f * d * d);
    }
    int s = senders[e], rc = receivers[e];
    const float* n0p = nodes0 + s * NC;
    const float* n1p = nodes1 + s * NC * 3;
    float* o0 = out0 + rc * 32;
    float* o1 = out1 + rc * 144;
    float pey = Y1CF * ey, pez = Y1CF * ez, pex = Y1CF * ex;
    for (int c = 0; c < NC; c++) {
        float rad00 = 0.f, rad01 = 0.f, rad10 = 0.f, rad11 = 0.f;
#pragma unroll
        for (int b = 0; b < 5; b++) {
            rad00 = fmaf(rbf[b], c00[c * 5 + b], rad00);
            rad01 = fmaf(rbf[b], c01[c * 5 + b], rad01);
            rad10 = fmaf(rbf[b], c10[c * 5 + b], rad10);
            rad11 = fmaf(rbf[b], c11[c * 5 + b], rad11);
        }
        float n0 = n0p[c];
        float n1a = n1p[3 * c + 0], n1b = n1p[3 * c + 1], n1c = n1p[3 * c + 2];
        float f11a = rad11 * pey, f11b = rad11 * pez, f11c = rad11 * pex;
        atomicAdd(&o0[c], w000[c] * n0 * rad00 * Y00F);
        atomicAdd(&o0[16 + c], w110[c] * RS3 * (n1a * f11a + n1b * f11b + n1c * f11c));
        float kA = w011[c] * n0 * rad01;
        atomicAdd(&o1[3 * c + 0], kA * pey);
        atomicAdd(&o1[3 * c + 1], kA * pez);
        atomicAdd(&o1[3 * c + 2], kA * pex);
        float kB = w101[c] * rad10 * Y00F;
        atomicAdd(&o1[3 * (16 + c) + 0], kB * n1a);
        atomicAdd(&o1[3 * (16 + c) + 1], kB * n1b);
        atomicAdd(&o1[3 * (16 + c) + 2], kB * n1c);
        float kC = w111[c] * RS2;
        atomicAdd(&o1[3 * (32 + c) + 0], kC * (n1b * f11c - n1c * f11b));
        atomicAdd(&o1[3 * (32 + c) + 1], kC * (n1c * f11a - n1a * f11c));
        atomicAdd(&o1[3 * (32 + c) + 2], kC * (n1a * f11b - n1b * f11a));
    }
}

extern "C" void kernel_launch(void* const* d_in, const int* in_sizes, int n_in,
                              void* d_out, int out_size, void* d_ws, size_t ws_size,
                              hipStream_t stream) {
    const float* coords    = (const float*)d_in[0];
    const float* nodes0    = (const float*)d_in[1];
    const float* nodes1    = (const float*)d_in[2];
    const float* edges     = (const float*)d_in[3];
    const int*   senders   = (const int*)  d_in[4];
    const int*   receivers = (const int*)  d_in[5];
    const float* c00       = (const float*)d_in[6];
    const float* c01       = (const float*)d_in[7];
    const float* c10       = (const float*)d_in[8];
    const float* c11       = (const float*)d_in[9];
    const float* w000      = (const float*)d_in[10];
    const float* w011      = (const float*)d_in[11];
    const float* w101      = (const float*)d_in[12];
    const float* w110      = (const float*)d_in[13];
    const float* w111      = (const float*)d_in[14];

    float* out  = (float*)d_out;
    float* out0 = out + 3 * NN;
    float* out1 = out + 3 * NN + NN * 2 * NC;

    size_t bins_bytes  = (size_t)NN * PBIN * 8;
    size_t nodes_bytes = (size_t)NN * NC * 8;
    size_t need1 = bins_bytes + nodes_bytes + (size_t)(NN + 1 + 4096) * 4;

    if (ws_size >= need1) {
        nu2* bins      = (nu2*)d_ws;
        nu2* nodes_h   = (nu2*)((char*)d_ws + bins_bytes);
        int* cnt       = (int*)((char*)d_ws + bins_bytes + nodes_bytes);  // NN
        int* ovf_count = cnt + NN;                                        // 1
        int* ovf_list  = ovf_count + 1;                                   // 4096

        init1_kernel<<<(NN * NC + 255) / 256, 256, 0, stream>>>(
            coords, nodes0, nodes1, out, cnt, ovf_count, nodes_h);
        bin_kernel<<<(E_EDGES + 255) / 256, 256, 0, stream>>>(
            edges, senders, receivers, cnt, bins, ovf_count, ovf_list);
        gather1_kernel<<<NN / 4, 256, 0, stream>>>(
            bins, cnt, nodes_h,
            c00, c01, c10, c11, w000, w011, w101, w110, w111, out0, out1);
        cleanup_kernel<<<1, 256, 0, stream>>>(
            ovf_count, ovf_list, edges, senders, receivers, nodes0, nodes1,
            c00, c01, c10, c11, w000, w011, w101, w110, w111, out0, out1);
    } else {
        init_out_fb<<<(out_size + 255) / 256, 256, 0, stream>>>(coords, out, out_size);
        tp_edges_fb<<<(E_EDGES + 255) / 256, 256, 0, stream>>>(
            edges, senders, receivers, nodes0, nodes1,
            c00, c01, c10, c11, w000, w011, w101, w110, w111, out0, out1);
    }
}

// Round 15
// 161.603 us; speedup vs baseline: 1.0725x; 1.0209x over previous
//
#include <hip/hip_runtime.h>
#include <hip/hip_fp16.h>

#define E_EDGES 640000
#define NN 20000
#define NC 16
#define PBIN 64   // fixed bin capacity per node (Poisson(32) tail ~1e-7)

#define Y00F 0.28209479177387814f
#define Y1CF 0.4886025119029199f
#define RS3  0.5773502691896258f
#define RS2  0.7071067811865476f

typedef unsigned int nu2 __attribute__((ext_vector_type(2)));

__device__ __forceinline__ unsigned pack2h(float a, float b) {
    unsigned short ua = __half_as_ushort(__float2half(a));
    unsigned short ub = __half_as_ushort(__float2half(b));
    return (unsigned)ua | ((unsigned)ub << 16);
}
__device__ __forceinline__ float lo_h(unsigned u) {
    return __half2float(__ushort_as_half((unsigned short)(u & 0xffffu)));
}
__device__ __forceinline__ float hi_h(unsigned u) {
    return __half2float(__ushort_as_half((unsigned short)(u >> 16)));
}

// 8-byte record: {h(ey)|h(ez)<<16, h(ex)|sender<<16}  (sender < 65536)
// gather recomputes r2, A=exp(-0.7r2), t=exp(1.225r); rbf_b = A*t^b*K_b
// node cache: nodes_h[s*16+c] = {h(n0),h(n1a) | h(n1b),h(n1c)}  (8 B)

__global__ void init1_kernel(const float* __restrict__ coords,
                             const float* __restrict__ nodes0,
                             const float* __restrict__ nodes1,
                             float* __restrict__ out,
                             int* __restrict__ cnt,
                             int* __restrict__ ovf_count,
                             nu2* __restrict__ nodes_h) {
    int i = blockIdx.x * blockDim.x + threadIdx.x;
    if (i < 3 * NN) out[i] = coords[i];
    if (i < NN) cnt[i] = 0;
    if (i == 0) *ovf_count = 0;
    if (i < NN * NC) {
        float n0 = nodes0[i];
        const float* n1p = nodes1 + i * 3;
        nu2 v;
        v.x = pack2h(n0, n1p[0]);
        v.y = pack2h(n1p[1], n1p[2]);
        nodes_h[i] = v;
    }
}

__global__ void bin_kernel(const float* __restrict__ edges,
                           const int* __restrict__ senders,
                           const int* __restrict__ receivers,
                           int* __restrict__ cnt,
                           nu2* __restrict__ bins,
                           int* __restrict__ ovf_count,
                           int* __restrict__ ovf_list) {
    int e = blockIdx.x * blockDim.x + threadIdx.x;
    if (e >= E_EDGES) return;
    float ex = edges[3 * e + 0];
    float ey = edges[3 * e + 1];
    float ez = edges[3 * e + 2];
    int s  = senders[e];
    int rc = receivers[e];
    int pos = atomicAdd(&cnt[rc], 1);
    if (pos < PBIN) {
        nu2 rec;
        rec.x = pack2h(ey, ez);
        rec.y = (unsigned)__half_as_ushort(__float2half(ex)) | ((unsigned)s << 16);
        bins[(size_t)rc * PBIN + pos] = rec;
    } else {
        int k = atomicAdd(ovf_count, 1);
        if (k < 4096) ovf_list[k] = e;
    }
}

// gather: ONE wave per node, 4 nodes per block.
// Phase A: lane l loads record l (one coalesced 512B load per wave).
// Phase B: WAVE-UNIFORM loop (all lanes run ceil(n/4) iterations, shfl
// always fully converged); accumulate predicated by idx < n.
__global__ __launch_bounds__(256) void gather1_kernel(
    const nu2*    __restrict__ bins,
    const int*    __restrict__ cnt,
    const nu2*    __restrict__ nodes_h,
    const float*  __restrict__ c00, const float* __restrict__ c01,
    const float*  __restrict__ c10, const float* __restrict__ c11,
    const float*  __restrict__ w000, const float* __restrict__ w011,
    const float*  __restrict__ w101, const float* __restrict__ w110,
    const float*  __restrict__ w111,
    float* __restrict__ out0, float* __restrict__ out1)
{
    int t    = threadIdx.x;
    int node = blockIdx.x * 4 + (t >> 6);      // NN multiple of 4
    int lane = t & 63;
    int c    = lane & 15;
    int j    = lane >> 4;                      // channel-group 0..3

    const float KB[5] = {1.0f, 0.58512723f, 0.11721218f, 0.00803909f, 1.8876652e-4f};
    float k00[5], k01[5], k10[5], k11[5];
#pragma unroll
    for (int b = 0; b < 5; b++) {
        k00[b] = c00[c * 5 + b] * KB[b];
        k01[b] = c01[c * 5 + b] * KB[b];
        k10[b] = c10[c * 5 + b] * KB[b];
        k11[b] = c11[c * 5 + b] * KB[b];
    }

    int n = cnt[node];
    n = (n < PBIN) ? n : PBIN;
    const nu2* base = bins + (size_t)node * PBIN;

    // Phase A: whole bin into wave registers (one coalesced load)
    nu2 R = {0u, 0u};
    if (lane < n) R = base[lane];
    int Rx = (int)R.x, Ry = (int)R.y;

    float a000 = 0.f, a110 = 0.f;
    float a011x = 0.f, a011y = 0.f, a011z = 0.f;
    float a101x = 0.f, a101y = 0.f, a101z = 0.f;
    float a111x = 0.f, a111y = 0.f, a111z = 0.f;

#define HORNER(k, t) fmaf((t), fmaf((t), fmaf((t), fmaf((t), k[4], k[3]), k[2]), k[1]), k[0])

    int iters = (n + 3) >> 2;     // wave-uniform trip count
    int idx = j;
    // prefetch record-y + node row for this group's first record
    unsigned ry = (unsigned)__shfl(Ry, idx & 63, 64);
    nu2 nh = {0u, 0u};
    if (idx < n) nh = nodes_h[(ry >> 16) * NC + c];

    for (int k = 0; k < iters; k++) {
        unsigned rx  = (unsigned)__shfl(Rx, idx & 63, 64);
        unsigned ryc = ry;
        nu2 nhc = nh;
        int nidx = idx + 4;
        // prefetch next (shfl converged; wrap of index is harmless)
        ry = (unsigned)__shfl(Ry, nidx & 63, 64);
        if (nidx < n) nh = nodes_h[(ry >> 16) * NC + c];

        if (idx < n) {
            float py = lo_h(rx), pz = hi_h(rx);
            float px = lo_h(ryc);
            float r2 = fmaf(px, px, fmaf(py, py, pz * pz));
            float r  = sqrtf(r2);
            float Af = __expf(-0.7f * r2);
            float tf = __expf(1.225f * r);
            float rad00 = Af * HORNER(k00, tf);
            float rad01 = Af * HORNER(k01, tf);
            float rad10 = Af * HORNER(k10, tf);
            float rad11 = Af * HORNER(k11, tf);
            float n0  = lo_h(nhc.x), n1a = hi_h(nhc.x);
            float n1b = lo_h(nhc.y), n1c = hi_h(nhc.y);
            a000 = fmaf(n0, rad00, a000);
            a110 = fmaf(rad11, n1a * py + n1b * pz + n1c * px, a110);
            float kA = n0 * rad01;
            a011x = fmaf(kA, py, a011x);
            a011y = fmaf(kA, pz, a011y);
            a011z = fmaf(kA, px, a011z);
            a101x = fmaf(rad10, n1a, a101x);
            a101y = fmaf(rad10, n1b, a101y);
            a101z = fmaf(rad10, n1c, a101z);
            a111x = fmaf(rad11, n1b * px - n1c * pz, a111x);
            a111y = fmaf(rad11, n1c * py - n1a * px, a111y);
            a111z = fmaf(rad11, n1a * pz - n1b * py, a111z);
        }
        idx = nidx;
    }
#undef HORNER

    // intra-wave reduce over j (lane bits 4,5) — converged
#define RED(v) v += __shfl_xor(v, 16, 64); v += __shfl_xor(v, 32, 64)
    RED(a000); RED(a110);
    RED(a011x); RED(a011y); RED(a011z);
    RED(a101x); RED(a101y); RED(a101z);
    RED(a111x); RED(a111y); RED(a111z);
#undef RED

    if (j == 0) {
        // Y1C folded here (records hold raw e)
        float s000 = w000[c] * Y00F;
        float s110 = w110[c] * RS3 * Y1CF;
        float s011 = w011[c] * Y1CF;
        float s101 = w101[c] * Y00F;
        float s111 = w111[c] * RS2 * Y1CF;

        out0[node * 32 + c]      = s000 * a000;
        out0[node * 32 + 16 + c] = s110 * a110;

        float* o1 = out1 + node * 144;
        o1[3 * c + 0] = s011 * a011x;
        o1[3 * c + 1] = s011 * a011y;
        o1[3 * c + 2] = s011 * a011z;
        o1[3 * (16 + c) + 0] = s101 * a101x;
        o1[3 * (16 + c) + 1] = s101 * a101y;
        o1[3 * (16 + c) + 2] = s101 * a101z;
        o1[3 * (32 + c) + 0] = s111 * a111x;
        o1[3 * (32 + c) + 1] = s111 * a111y;
        o1[3 * (32 + c) + 2] = s111 * a111z;
    }
}

// cleanup: overflow edges (expected 0) — exact atomic path, after gather
__global__ void cleanup_kernel(
    const int* __restrict__ ovf_count, const int* __restrict__ ovf_list,
    const float* __restrict__ edges, const int* __restrict__ senders,
    const int* __restrict__ receivers,
    const float* __restrict__ nodes0, const float* __restrict__ nodes1,
    const float* __restrict__ c00, const float* __restrict__ c01,
    const float* __restrict__ c10, const float* __restrict__ c11,
    const float* __restrict__ w000, const float* __restrict__ w011,
    const float* __restrict__ w101, const float* __restrict__ w110,
    const float* __restrict__ w111,
    float* __restrict__ out0, float* __restrict__ out1)
{
    int nov = *ovf_count;
    if (nov > 4096) nov = 4096;
    for (int k = threadIdx.x; k < nov; k += blockDim.x) {
        int e = ovf_list[k];
        float ex = edges[3 * e + 0], ey = edges[3 * e + 1], ez = edges[3 * e + 2];
        float r = sqrtf(ex * ex + ey * ey + ez * ez);
        float rbf[5];
#pragma unroll
        for (int b = 0; b < 5; b++) {
            float d = r - 0.875f * (float)b;
            rbf[b] = __expf(-0.7f * d * d);
        }
        int s = senders[e], rc = receivers[e];
        const float* n0p = nodes0 + s * NC;
        const float* n1p = nodes1 + s * NC * 3;
        float* o0 = out0 + rc * 32;
        float* o1 = out1 + rc * 144;
        float pey = Y1CF * ey, pez = Y1CF * ez, pex = Y1CF * ex;
        for (int c = 0; c < NC; c++) {
            float rad00 = 0.f, rad01 = 0.f, rad10 = 0.f, rad11 = 0.f;
#pragma unroll
            for (int b = 0; b < 5; b++) {
                rad00 = fmaf(rbf[b], c00[c * 5 + b], rad00);
                rad01 = fmaf(rbf[b], c01[c * 5 + b], rad01);
                rad10 = fmaf(rbf[b], c10[c * 5 + b], rad10);
                rad11 = fmaf(rbf[b], c11[c * 5 + b], rad11);
            }
            float n0 = n0p[c];
            float n1a = n1p[3 * c + 0], n1b = n1p[3 * c + 1], n1c = n1p[3 * c + 2];
            float f11a = rad11 * pey, f11b = rad11 * pez, f11c = rad11 * pex;
            atomicAdd(&o0[c], w000[c] * n0 * rad00 * Y00F);
            atomicAdd(&o0[16 + c], w110[c] * RS3 * (n1a * f11a + n1b * f11b + n1c * f11c));
            float kA = w011[c] * n0 * rad01;
            atomicAdd(&o1[3 * c + 0], kA * pey);
            atomicAdd(&o1[3 * c + 1], kA * pez);
            atomicAdd(&o1[3 * c + 2], kA * pex);
            float kB = w101[c] * rad10 * Y00F;
            atomicAdd(&o1[3 * (16 + c) + 0], kB * n1a);
            atomicAdd(&o1[3 * (16 + c) + 1], kB * n1b);
            atomicAdd(&o1[3 * (16 + c) + 2], kB * n1c);
            float kC = w111[c] * RS2;
            atomicAdd(&o1[3 * (32 + c) + 0], kC * (n1b * f11c - n1c * f11b));
            atomicAdd(&o1[3 * (32 + c) + 1], kC * (n1c * f11a - n1a * f11c));
            atomicAdd(&o1[3 * (32 + c) + 2], kC * (n1a * f11b - n1b * f11a));
        }
    }
}

// ======================= fallback: pure atomic ============================
__global__ void init_out_fb(const float* __restrict__ coords,
                            float* __restrict__ out, int out_size) {
    int i = blockIdx.x * blockDim.x + threadIdx.x;
    if (i < 3 * NN) out[i] = coords[i];
    else if (i < out_size) out[i] = 0.0f;
}

__global__ __launch_bounds__(256) void tp_edges_fb(
    const float* __restrict__ edges, const int* __restrict__ senders,
    const int* __restrict__ receivers, const float* __restrict__ nodes0,
    const float* __restrict__ nodes1,
    const float* __restrict__ c00, const float* __restrict__ c01,
    const float* __restrict__ c10, const float* __restrict__ c11,
    const float* __restrict__ w000, const float* __restrict__ w011,
    const float* __restrict__ w101, const float* __restrict__ w110,
    const float* __restrict__ w111,
    float* __restrict__ out0, float* __restrict__ out1) {
    int e = blockIdx.x * blockDim.x + threadIdx.x;
    if (e >= E_EDGES) return;
    float ex = edges[3 * e + 0], ey = edges[3 * e + 1], ez = edges[3 * e + 2];
    float r = sqrtf(ex * ex + ey * ey + ez * ez);
    float rbf[5];
#pragma unroll
    for (int b = 0; b < 5; b++) {
        float d = r - 0.875f * (float)b;
        rbf[b] = __expf(-0.7f * d * d);
    }
    int s = senders[e], rc = receivers[e];
    const float* n0p = nodes0 + s * NC;
    const float* n1p = nodes1 + s * NC * 3;
    float* o0 = out0 + rc * 32;
    float* o1 = out1 + rc * 144;
    float pey = Y1CF * ey, pez = Y1CF * ez, pex = Y1CF * ex;
    for (int c = 0; c < NC; c++) {
        float rad00 = 0.f, rad01 = 0.f, rad10 = 0.f, rad11 = 0.f;
#pragma unroll
        for (int b = 0; b < 5; b++) {
            rad00 = fmaf(rbf[b], c00[c * 5 + b], rad00);
            rad01 = fmaf(rbf[b], c01[c * 5 + b], rad01);
            rad10 = fmaf(rbf[b], c10[c * 5 + b], rad10);
            rad11 = fmaf(rbf[b], c11[c * 5 + b], rad11);
        }
        float n0 = n0p[c];
        float n1a = n1p[3 * c + 0], n1b = n1p[3 * c + 1], n1c = n1p[3 * c + 2];
        float f11a = rad11 * pey, f11b = rad11 * pez, f11c = rad11 * pex;
        atomicAdd(&o0[c], w000[c] * n0 * rad00 * Y00F);
        atomicAdd(&o0[16 + c], w110[c] * RS3 * (n1a * f11a + n1b * f11b + n1c * f11c));
        float kA = w011[c] * n0 * rad01;
        atomicAdd(&o1[3 * c + 0], kA * pey);
        atomicAdd(&o1[3 * c + 1], kA * pez);
        atomicAdd(&o1[3 * c + 2], kA * pex);
        float kB = w101[c] * rad10 * Y00F;
        atomicAdd(&o1[3 * (16 + c) + 0], kB * n1a);
        atomicAdd(&o1[3 * (16 + c) + 1], kB * n1b);
        atomicAdd(&o1[3 * (16 + c) + 2], kB * n1c);
        float kC = w111[c] * RS2;
        atomicAdd(&o1[3 * (32 + c) + 0], kC * (n1b * f11c - n1c * f11b));
        atomicAdd(&o1[3 * (32 + c) + 1], kC * (n1c * f11a - n1a * f11c));
        atomicAdd(&o1[3 * (32 + c) + 2], kC * (n1a * f11b - n1b * f11a));
    }
}

extern "C" void kernel_launch(void* const* d_in, const int* in_sizes, int n_in,
                              void* d_out, int out_size, void* d_ws, size_t ws_size,
                              hipStream_t stream) {
    const float* coords    = (const float*)d_in[0];
    const float* nodes0    = (const float*)d_in[1];
    const float* nodes1    = (const float*)d_in[2];
    const float* edges     = (const float*)d_in[3];
    const int*   senders   = (const int*)  d_in[4];
    const int*   receivers = (const int*)  d_in[5];
    const float* c00       = (const float*)d_in[6];
    const float* c01       = (const float*)d_in[7];
    const float* c10       = (const float*)d_in[8];
    const float* c11       = (const float*)d_in[9];
    const float* w000      = (const float*)d_in[10];
    const float* w011      = (const float*)d_in[11];
    const float* w101      = (const float*)d_in[12];
    const float* w110      = (const float*)d_in[13];
    const float* w111      = (const float*)d_in[14];

    float* out  = (float*)d_out;
    float* out0 = out + 3 * NN;
    float* out1 = out + 3 * NN + NN * 2 * NC;

    size_t bins_bytes  = (size_t)NN * PBIN * 8;
    size_t nodes_bytes = (size_t)NN * NC * 8;
    size_t need1 = bins_bytes + nodes_bytes + (size_t)(NN + 1 + 4096) * 4;

    if (ws_size >= need1) {
        nu2* bins      = (nu2*)d_ws;
        nu2* nodes_h   = (nu2*)((char*)d_ws + bins_bytes);
        int* cnt       = (int*)((char*)d_ws + bins_bytes + nodes_bytes);  // NN
        int* ovf_count = cnt + NN;                                        // 1
        int* ovf_list  = ovf_count + 1;                                   // 4096

        init1_kernel<<<(NN * NC + 255) / 256, 256, 0, stream>>>(
            coords, nodes0, nodes1, out, cnt, ovf_count, nodes_h);
        bin_kernel<<<(E_EDGES + 255) / 256, 256, 0, stream>>>(
            edges, senders, receivers, cnt, bins, ovf_count, ovf_list);
        gather1_kernel<<<NN / 4, 256, 0, stream>>>(
            bins, cnt, nodes_h,
            c00, c01, c10, c11, w000, w011, w101, w110, w111, out0, out1);
        cleanup_kernel<<<1, 256, 0, stream>>>(
            ovf_count, ovf_list, edges, senders, receivers, nodes0, nodes1,
            c00, c01, c10, c11, w000, w011, w101, w110, w111, out0, out1);
    } else {
        init_out_fb<<<(out_size + 255) / 256, 256, 0, stream>>>(coords, out, out_size);
        tp_edges_fb<<<(E_EDGES + 255) / 256, 256, 0, stream>>>(
            edges, senders, receivers, nodes0, nodes1,
            c00, c01, c10, c11, w000, w011, w101, w110, w111, out0, out1);
    }
}